// Round 14
// baseline (382.832 us; speedup 1.0000x reference)
//
#include <hip/hip_runtime.h>

#define N_NODES 50000
#define N_EDGES 300000
#define DIM 256
#define HID 128
#define INP 64
#define BATCH 4096
#define SEQ 50
#define SCAN_BLOCKS 196   // ceil(50000/256)

typedef float f32x2 __attribute__((ext_vector_type(2)));
typedef float f32x4 __attribute__((ext_vector_type(4)));
typedef __bf16 bf16x2 __attribute__((ext_vector_type(2)));
typedef __bf16 bf16x4 __attribute__((ext_vector_type(4)));
typedef __bf16 bf16x8 __attribute__((ext_vector_type(8)));

#define L2E  1.4426950408889634f
#define L2E2 2.8853900817779268f

// fast activations: v_rcp_f32 instead of IEEE divide (~1 ulp, inf-safe)
__device__ __forceinline__ float sigmoidf_(float x) {
    return __builtin_amdgcn_rcpf(1.0f + __expf(-x));
}
__device__ __forceinline__ float tanhf_(float x) {
    return 1.0f - 2.0f * __builtin_amdgcn_rcpf(1.0f + __expf(2.0f * x));
}
// prescaled variants: inputs already multiplied by log2e (sig) / 2*log2e (tanh)
// via weight/bias prescale in k_prep -> saves the per-activation log2e mul.
// R2 post-mortem: __builtin_exp2f lowers to llvm.exp2 -> backend emits a
// denormal-range GUARD (~6 ops) -> VALU +45%. __builtin_amdgcn_exp2f is the
// raw v_exp_f32 (1 op); gate inputs are O(1), denormals impossible. (R3 ✓)
__device__ __forceinline__ float sigp_(float y) {
    return __builtin_amdgcn_rcpf(1.0f + __builtin_amdgcn_exp2f(-y));
}
__device__ __forceinline__ float tanhp_(float y) {
    return 1.0f - 2.0f * __builtin_amdgcn_rcpf(1.0f + __builtin_amdgcn_exp2f(y));
}
__device__ __forceinline__ float tanhc_(float x) {   // runtime (unscaled) arg
    return 1.0f - 2.0f * __builtin_amdgcn_rcpf(1.0f + __builtin_amdgcn_exp2f(x * L2E2));
}

// Workgroup barrier WITHOUT the vmcnt(0) drain __syncthreads() emits.
__device__ __forceinline__ void barrier_lds_only() {
    asm volatile("s_waitcnt lgkmcnt(0)" ::: "memory");
    __builtin_amdgcn_s_barrier();
}

// BANKED lessons:
// R8: cooperative grid.sync() ~110us/sync at 1172 blocks (452us spin kernel).
//     Launch gaps are only ~1-2us; non-lstm time is kernel EXECUTION.
// R9: coarse-histogram atomics (300K adds over 196 lines = ~1530 same-address
//     collisions each) serialize at L2 -> 180us. Atomic cost scales with
//     per-address collisions.
// R11: serial poles hide inside big grids (prep's 1-block colsum).
// R12: k_head 1 block/CU x 4 waves = zero TLP -> ~8us; 8 waves -> ~4us.
// R13: top-5 saturated by 102us k_lstm instances -> split lstm into two
//     half-batch launches (~51us each, cost ~1 gap) to expose the tail
//     kernels + their counters. ~140us of tail remains unattributed by
//     bottom-up models (suspect: anomalous kernel OR harness reset memsets).

// ---------------- fused prep: weight packs + w2 partials + zeroing + emb->bf16
// blocks 0..767: lstm weight frags | 768..1279: gate_W pack | 1280..1535: risk_W1
// 1536..1567: w2 colsum partials (32 blocks x 8 rows, coalesced — R11)
// 1568..1763: zero deg | 1764..1812: zero flagC | 1813..1861: zero flagB
// 1862..8111: node_emb f32->bf16 (R4)
__global__ void k_prep(const float* __restrict__ Wih_f, const float* __restrict__ Whh_f,
                       const float* __restrict__ Wih_b, const float* __restrict__ Whh_b,
                       const float* __restrict__ gate_W, const float* __restrict__ risk_W1,
                       const float* __restrict__ risk_W2,
                       const float* __restrict__ node_emb,
                       __bf16* __restrict__ w2frag, __bf16* __restrict__ gwp,
                       __bf16* __restrict__ w1p, float* __restrict__ p32,
                       int* __restrict__ deg, int* __restrict__ flagCi,
                       int* __restrict__ flagBi, __bf16* __restrict__ embh) {
    int bid = blockIdx.x, tid = threadIdx.x;
    if (bid < 768) {
        // LSTM W=[Wih|Whh] -> frags: per dir frag=(w*4+g)*6+kc, within=lane*8+j
        // weights prescaled: i,f,o gates x log2e ; g (cell) gate x 2*log2e
        int idx = bid * 256 + tid;              // 2*192*512 = 196608
        int dir = idx / 98304;
        int rem = idx % 98304;
        int frag = rem >> 9;
        int within = rem & 511;
        int lane = within >> 3, j = within & 7;
        int kc = frag % 6;
        int wg = frag / 6;
        int g = wg & 3, w = wg >> 2;
        int n = g * 128 + w * 16 + (lane & 15);
        int k = kc * 32 + (lane >> 4) * 8 + j;
        const float* Wih = dir ? Wih_b : Wih_f;
        const float* Whh = dir ? Whh_b : Whh_f;
        float v = (k < 64) ? Wih[n * 64 + k] : Whh[n * 128 + (k - 64)];
        float sc = (g == 2) ? L2E2 : L2E;
        w2frag[idx] = (__bf16)(v * sc);
    } else if (bid < 1280) {
        int idx = (bid - 768) * 256 + tid;      // 131072
        int frag = idx >> 9, within = idx & 511;
        int lane = within >> 3, j = within & 7;
        int kc = frag % 16, T = frag / 16;
        int n = T * 16 + (lane & 15);
        int k = kc * 32 + (lane >> 4) * 8 + j;
        gwp[idx] = (__bf16)gate_W[(size_t)n * 512 + k];
    } else if (bid < 1536) {
        int idx = (bid - 1280) * 256 + tid;     // 65536
        int frag = idx >> 9, within = idx & 511;
        int lane = within >> 3, j = within & 7;
        int kc = frag % 8, T = frag / 8;
        int n = T * 16 + (lane & 15);
        int k = kc * 32 + (lane >> 4) * 8 + j;
        w1p[idx] = (__bf16)risk_W1[(size_t)n * 256 + k];
    } else if (bid < 1568) {
        // w2 colsum partials: block j sums rows [j*8, j*8+8), coalesced rows
        int j = bid - 1536;
        int k = tid;
        float s = 0.0f;
#pragma unroll
        for (int r = 0; r < 8; r++) s += risk_W2[(size_t)(j * 8 + r) * 256 + k];
        p32[j * 256 + k] = s;
    } else if (bid < 1764) {
        int i = (bid - 1568) * 256 + tid;
        if (i < N_NODES) deg[i] = 0;
    } else if (bid < 1813) {
        int i = (bid - 1764) * 256 + tid;       // 49*256 = 12544 ints = 50176 B
        flagCi[i] = 0;
    } else if (bid < 1862) {
        int i = (bid - 1813) * 256 + tid;
        flagBi[i] = 0;
    } else {
        // emb convert: 12,800,000 elems / 8 per thread / 256 thr = 6250 blocks
        int idx = (bid - 1862) * 2048 + tid * 8;
        f32x4 a = *(const f32x4*)(node_emb + idx);
        f32x4 b = *(const f32x4*)(node_emb + idx + 4);
        bf16x8 o;
        o[0] = (__bf16)a.x; o[1] = (__bf16)a.y; o[2] = (__bf16)a.z; o[3] = (__bf16)a.w;
        o[4] = (__bf16)b.x; o[5] = (__bf16)b.y; o[6] = (__bf16)b.z; o[7] = (__bf16)b.w;
        *(bf16x8*)(embh + idx) = o;
    }
}

// ---------------- GCN: counting sort by head ----------------
// R10: deg histogram only (50K counters, ~6 collisions/addr — fine).
// Batch flags set here (prep zeroed them; later launch -> no race).
__global__ void k_hist(const int* __restrict__ head, const int* __restrict__ nidx,
                       int* __restrict__ deg, char* __restrict__ flagB,
                       char* __restrict__ flagC) {
    int e = blockIdx.x * 256 + threadIdx.x;
    if (e < N_EDGES) atomicAdd(&deg[head[e]], 1);
    if (e < BATCH) {
        int n = nidx[e];
        flagB[n] = 1;
        flagC[n] = 1;
    }
}

// per-block sums of deg (sequential read, LDS reduce) — R7-proven form.
// R11: extra block (bid==SCAN_BLOCKS) folds the 32 w2 partials -> w2s[0..255]
// and reduces risk_b2 -> w2s[256] (moved out of k_prep's serial block).
__global__ void k_bsum(const int* __restrict__ deg, int* __restrict__ bsum,
                       const float* __restrict__ p32, const float* __restrict__ risk_b2,
                       float* __restrict__ w2s) {
    __shared__ int red[256];
    __shared__ float redf[256];
    int bid = blockIdx.x, tid = threadIdx.x;
    if (bid < SCAN_BLOCKS) {
        int n = bid * 256 + tid;
        red[tid] = (n < N_NODES) ? deg[n] : 0;
        __syncthreads();
        for (int st = 128; st > 0; st >>= 1) {
            if (tid < st) red[tid] += red[tid + st];
            __syncthreads();
        }
        if (tid == 0) bsum[bid] = red[0];
    } else {
        float s = 0.0f;
#pragma unroll
        for (int j = 0; j < 32; j++) s += p32[j * 256 + tid];
        w2s[tid] = s;
        redf[tid] = risk_b2[tid];
        __syncthreads();
        for (int st = 128; st > 0; st >>= 1) {
            if (tid < st) redf[tid] += redf[tid + st];
            __syncthreads();
        }
        if (tid == 0) w2s[256] = redf[0];
    }
}

// R7: scanb folded in — each block computes its own exclusive block-prefix
// from bsum (second LDS scan in the same barrier loop).
__global__ void k_scan2(const int* __restrict__ deg, const int* __restrict__ bsum,
                        int* __restrict__ offsets, int* __restrict__ cursor) {
    __shared__ int s[256];
    __shared__ int sb[256];
    int i = threadIdx.x;
    int n = blockIdx.x * 256 + i;
    int v = (n < N_NODES) ? deg[n] : 0;
    s[i] = v;
    sb[i] = (i < SCAN_BLOCKS) ? bsum[i] : 0;
    __syncthreads();
    for (int st = 1; st < 256; st <<= 1) {
        int add = (i >= st) ? s[i - st] : 0;
        int addb = (i >= st) ? sb[i - st] : 0;
        __syncthreads();
        s[i] += add;
        sb[i] += addb;
        __syncthreads();
    }
    int boff = (blockIdx.x > 0) ? sb[blockIdx.x - 1] : 0;   // exclusive block prefix
    if (n < N_NODES) {
        int off = boff + s[i] - v;
        offsets[n] = off;
        cursor[n] = off;
    }
    if (n == 0) offsets[N_NODES] = N_EDGES;
}

// R9 (kept): k_flag folded in — per-edge tail-flag: flagC[tail]=1 where
// flagB[head]. flagB marks batch nodes only -> no cascade; identical flag set.
__global__ void k_place(const int* __restrict__ head, const int* __restrict__ tail,
                        const int* __restrict__ etype, int* __restrict__ cursor,
                        int* __restrict__ sorted, const char* __restrict__ flagB,
                        char* __restrict__ flagC) {
    int e = blockIdx.x * 256 + threadIdx.x;
    if (e >= N_EDGES) return;
    int h = head[e];
    int pos = atomicAdd(&cursor[h], 1);
    int t = tail[e];
    sorted[pos] = t | (etype[e] << 16);   // tail<65536, etype<32
    if (flagB[h]) flagC[t] = 1;
}

// Hop 1: one wave per node; only flagged nodes (~43% of graph). No atomics.
// R4: bf16 src rows (8B/lane) + bf16 dst, f32 accumulate.
// R5 post-mortem: do NOT grid-fuse this with k_lstm (critical-path dilution).
__global__ void k_gather(const int* __restrict__ offsets, const int* __restrict__ sorted,
                         const float* __restrict__ relw, const __bf16* __restrict__ srch,
                         const char* __restrict__ flag, __bf16* __restrict__ dst) {
    int tid = threadIdx.x;
    int w = tid >> 6, lane = tid & 63;
    int n = blockIdx.x * 4 + w;
    if (n >= N_NODES) return;
    if (!flag[n]) return;
    int s = offsets[n], e = offsets[n + 1];
    f32x4 acc0 = (f32x4){0.f, 0.f, 0.f, 0.f};
    f32x4 acc1 = (f32x4){0.f, 0.f, 0.f, 0.f};
    f32x4 acc2 = (f32x4){0.f, 0.f, 0.f, 0.f};
    f32x4 acc3 = (f32x4){0.f, 0.f, 0.f, 0.f};
    int j = s;
    for (; j + 4 <= e; j += 4) {
        int p0 = sorted[j], p1 = sorted[j + 1], p2 = sorted[j + 2], p3 = sorted[j + 3];
        bf16x4 v0 = *(const bf16x4*)(srch + (size_t)(p0 & 0xFFFF) * DIM + lane * 4);
        bf16x4 v1 = *(const bf16x4*)(srch + (size_t)(p1 & 0xFFFF) * DIM + lane * 4);
        bf16x4 v2 = *(const bf16x4*)(srch + (size_t)(p2 & 0xFFFF) * DIM + lane * 4);
        bf16x4 v3 = *(const bf16x4*)(srch + (size_t)(p3 & 0xFFFF) * DIM + lane * 4);
        f32x4 f0 = (f32x4){(float)v0[0], (float)v0[1], (float)v0[2], (float)v0[3]};
        f32x4 f1 = (f32x4){(float)v1[0], (float)v1[1], (float)v1[2], (float)v1[3]};
        f32x4 f2 = (f32x4){(float)v2[0], (float)v2[1], (float)v2[2], (float)v2[3]};
        f32x4 f3 = (f32x4){(float)v3[0], (float)v3[1], (float)v3[2], (float)v3[3]};
        acc0 += f0 * *(const f32x4*)(relw + (p0 >> 16) * DIM + lane * 4);
        acc1 += f1 * *(const f32x4*)(relw + (p1 >> 16) * DIM + lane * 4);
        acc2 += f2 * *(const f32x4*)(relw + (p2 >> 16) * DIM + lane * 4);
        acc3 += f3 * *(const f32x4*)(relw + (p3 >> 16) * DIM + lane * 4);
    }
    for (; j < e; j++) {
        int p0 = sorted[j];
        bf16x4 v0 = *(const bf16x4*)(srch + (size_t)(p0 & 0xFFFF) * DIM + lane * 4);
        f32x4 f0 = (f32x4){(float)v0[0], (float)v0[1], (float)v0[2], (float)v0[3]};
        acc0 += f0 * *(const f32x4*)(relw + (p0 >> 16) * DIM + lane * 4);
    }
    acc0 = (acc0 + acc1) + (acc2 + acc3);
    float inv = 1.0f / fmaxf((float)(e - s), 1.0f);
    acc0 *= inv;
    bf16x4 o;
    o[0] = (__bf16)acc0.x; o[1] = (__bf16)acc0.y; o[2] = (__bf16)acc0.z; o[3] = (__bf16)acc0.w;
    *(bf16x4*)(dst + (size_t)n * DIM + lane * 4) = o;
}

// ---------------- BiLSTM: intra-wave 2-group software pipeline (R4 config) ---
// Block = 8 waves (512 thr), 2 groups x 16 samples, one dir.
// R13: launched as TWO half-batch dispatches (btile0 = 0, 64; grid (64,2))
// purely to unsaturate the top-5 profiler view (~51us each, per-block time
// unchanged — the 50-step chain is block-local). Cost: one launch gap.
// OCCUPANCY LOCKED at 2 waves/SIMD (R1/R2 spill, R6 no-coresidency).
// R3 opts: exp2-prescale, bias-as-C-init, ptr-increment prefetch, lgkm barriers.
__launch_bounds__(512)
__global__ void k_lstm(const float* __restrict__ ts, const __bf16* __restrict__ w2frag,
                       const float* __restrict__ b_f, const float* __restrict__ b_b,
                       float* __restrict__ temporal, int btile0) {
    int dir = blockIdx.y;
    int btile = blockIdx.x + btile0;    // 0..127 across the two launches
    int tid = threadIdx.x;
    int w = tid >> 6;          // wave 0..7
    int lane = tid & 63;
    int col = lane & 15, quad = lane >> 4;

    // [buf][row][k], rows 16, k: 0..63 = x, 64..191 = h, padded to 200 (16B-aligned rows)
    __shared__ __align__(16) __bf16 SA[2 * 16 * 200];
    __shared__ __align__(16) __bf16 SB[2 * 16 * 200];

    // zero h region of buf 0, both groups (h(-1) = 0)
    for (int i = tid; i < 2048; i += 512) {
        int m = i >> 7, k = i & 127;
        SA[m * 200 + 64 + k] = (__bf16)0.0f;
        SB[m * 200 + 64 + k] = (__bf16)0.0f;
    }

    const float* bias = dir ? b_b : b_f;
    f32x4 bva[4];
#pragma unroll
    for (int g = 0; g < 4; g++) {
        float b = bias[g * 128 + w * 16 + col] * ((g == 2) ? L2E2 : L2E);
        bva[g] = (f32x4){b, b, b, b};
    }

    const __bf16* wbase = w2frag + (size_t)dir * 98304 + (size_t)w * 12288;
    bf16x8 wreg[24];
#pragma unroll
    for (int f = 0; f < 24; f++) {
        wreg[f] = *(const bf16x8*)(wbase + (f << 9) + lane * 8);
    }

    // x staging: 16 rows x 64 cols per group; thread -> (sm, sc)
    int sm = tid >> 5, sc = (tid & 31) * 2;
    const float* xbA = ts + ((size_t)(btile * 32 + sm) * SEQ) * INP + sc;
    const float* xbB = ts + ((size_t)(btile * 32 + 16 + sm) * SEQ) * INP + sc;
    int t0i = dir ? (SEQ - 1) : 0;
    int t1i = dir ? (SEQ - 2) : 1;
    {   // stage x(0) for both groups into buf 0
        f32x2 xa = *(const f32x2*)(xbA + (size_t)t0i * INP);
        f32x2 xb = *(const f32x2*)(xbB + (size_t)t0i * INP);
        bf16x2 va; va[0] = (__bf16)xa.x; va[1] = (__bf16)xa.y;
        bf16x2 vb; vb[0] = (__bf16)xb.x; vb[1] = (__bf16)xb.y;
        *(bf16x2*)&SA[sm * 200 + sc] = va;
        *(bf16x2*)&SB[sm * 200 + sc] = vb;
    }
    f32x2 xpreA = *(const f32x2*)(xbA + (size_t)t1i * INP);
    f32x2 xpreB = *(const f32x2*)(xbB + (size_t)t1i * INP);
    // prefetch pointers start at x(t=2), walk +/-INP per step
    int xdelta = dir ? -INP : INP;
    const float* pA = xbA + (size_t)(dir ? (SEQ - 3) : 2) * INP;
    const float* pB = xbB + (size_t)(dir ? (SEQ - 3) : 2) * INP;

    f32x4 cA = (f32x4){0.f, 0.f, 0.f, 0.f}, hsA = cA;
    f32x4 cB = cA, hsB = cA;
    f32x4 accA[4], accB[4];
    int hwr = quad * 4 * 200 + 64 + w * 16 + col;   // h write base (row=quad*4, +r*200)
    int ard = col * 200 + quad * 8;                  // A-frag read base
    barrier_lds_only();

    // prologue MFMA-A(0) from SA buf 0 (bias folded in via C-init)
    {
        bf16x8 a0 = *(const bf16x8*)&SA[ard];
#pragma unroll
        for (int g = 0; g < 4; g++)
            accA[g] = __builtin_amdgcn_mfma_f32_16x16x32_bf16(a0, wreg[g * 6], bva[g], 0, 0, 0);
    }
#pragma unroll
    for (int kc = 1; kc < 6; kc++) {
        bf16x8 a0 = *(const bf16x8*)&SA[ard + kc * 32];
#pragma unroll
        for (int g = 0; g < 4; g++)
            accA[g] = __builtin_amdgcn_mfma_f32_16x16x32_bf16(a0, wreg[g * 6 + kc], accA[g], 0, 0, 0);
    }

    for (int t = 0; t < SEQ; t++) {
        int cb = (t & 1) * 3200;         // current buf offset
        int nb = ((t + 1) & 1) * 3200;   // next buf offset

        // ---- first half: MFMA-B(t) (reads SB[cb]) || cell-A(t) (writes SA[nb]) ----
        f32x2 xnA;
        bool ld = (t + 2 < SEQ);         // wave-uniform
        if (ld) { xnA = *(const f32x2*)pA; pA += xdelta; }
        {
            bf16x8 a0 = *(const bf16x8*)&SB[cb + ard];
#pragma unroll
            for (int g = 0; g < 4; g++)
                accB[g] = __builtin_amdgcn_mfma_f32_16x16x32_bf16(a0, wreg[g * 6], bva[g], 0, 0, 0);
        }
#pragma unroll
        for (int kc = 1; kc < 6; kc++) {
            bf16x8 a0 = *(const bf16x8*)&SB[cb + ard + kc * 32];
#pragma unroll
            for (int g = 0; g < 4; g++)
                accB[g] = __builtin_amdgcn_mfma_f32_16x16x32_bf16(a0, wreg[g * 6 + kc], accB[g], 0, 0, 0);
        }
#pragma unroll
        for (int r = 0; r < 4; r++) {
            float c = sigp_(accA[1][r]) * cA[r] + sigp_(accA[0][r]) * tanhp_(accA[2][r]);
            float h = sigp_(accA[3][r]) * tanhc_(c);
            cA[r] = c;
            hsA[r] += h;
            SA[nb + hwr + r * 200] = (__bf16)h;
        }
        if (t + 1 < SEQ) {
            bf16x2 v; v[0] = (__bf16)xpreA.x; v[1] = (__bf16)xpreA.y;
            *(bf16x2*)&SA[nb + sm * 200 + sc] = v;
            if (ld) xpreA = xnA;
        }
        barrier_lds_only();

        // ---- second half: MFMA-A(t+1) (reads SA[nb]) || cell-B(t) (writes SB[nb]) ----
        f32x2 xnB;
        if (ld) { xnB = *(const f32x2*)pB; pB += xdelta; }
        if (t + 1 < SEQ) {
            {
                bf16x8 a0 = *(const bf16x8*)&SA[nb + ard];
#pragma unroll
                for (int g = 0; g < 4; g++)
                    accA[g] = __builtin_amdgcn_mfma_f32_16x16x32_bf16(a0, wreg[g * 6], bva[g], 0, 0, 0);
            }
#pragma unroll
            for (int kc = 1; kc < 6; kc++) {
                bf16x8 a0 = *(const bf16x8*)&SA[nb + ard + kc * 32];
#pragma unroll
                for (int g = 0; g < 4; g++)
                    accA[g] = __builtin_amdgcn_mfma_f32_16x16x32_bf16(a0, wreg[g * 6 + kc], accA[g], 0, 0, 0);
            }
        }
#pragma unroll
        for (int r = 0; r < 4; r++) {
            float c = sigp_(accB[1][r]) * cB[r] + sigp_(accB[0][r]) * tanhp_(accB[2][r]);
            float h = sigp_(accB[3][r]) * tanhc_(c);
            cB[r] = c;
            hsB[r] += h;
            SB[nb + hwr + r * 200] = (__bf16)h;
        }
        if (t + 1 < SEQ) {
            bf16x2 v; v[0] = (__bf16)xpreB.x; v[1] = (__bf16)xpreB.y;
            *(bf16x2*)&SB[nb + sm * 200 + sc] = v;
            if (ld) xpreB = xnB;
        }
        barrier_lds_only();
    }

    // temporal[b][dir*128 + j] = mean over t of h
#pragma unroll
    for (int r = 0; r < 4; r++) {
        int j = w * 16 + col;
        int bA = btile * 32 + quad * 4 + r;
        int bB = bA + 16;
        temporal[(size_t)bA * 256 + dir * 128 + j] = hsA[r] * (1.0f / SEQ);
        temporal[(size_t)bB * 256 + dir * 128 + j] = hsB[r] * (1.0f / SEQ);
    }
}

// Hop 2 only at batch nodes, fused with struct = (emb + out1 + out2)/3.
// R4: bf16 out1/emb reads, f32 accumulate, f32 struct output (unchanged dtype).
__global__ void k_gather2(const int* __restrict__ nidx, const int* __restrict__ offsets,
                          const int* __restrict__ sorted, const float* __restrict__ relw,
                          const __bf16* __restrict__ out1h, const __bf16* __restrict__ embh,
                          float* __restrict__ structb) {
    int tid = threadIdx.x;
    int w = tid >> 6, lane = tid & 63;
    int b = blockIdx.x * 4 + w;          // grid = 1024 blocks, exact
    int n = nidx[b];
    int s = offsets[n], e = offsets[n + 1];
    f32x4 acc0 = (f32x4){0.f, 0.f, 0.f, 0.f};
    f32x4 acc1 = (f32x4){0.f, 0.f, 0.f, 0.f};
    f32x4 acc2 = (f32x4){0.f, 0.f, 0.f, 0.f};
    f32x4 acc3 = (f32x4){0.f, 0.f, 0.f, 0.f};
    int j = s;
    for (; j + 4 <= e; j += 4) {
        int p0 = sorted[j], p1 = sorted[j + 1], p2 = sorted[j + 2], p3 = sorted[j + 3];
        bf16x4 v0 = *(const bf16x4*)(out1h + (size_t)(p0 & 0xFFFF) * DIM + lane * 4);
        bf16x4 v1 = *(const bf16x4*)(out1h + (size_t)(p1 & 0xFFFF) * DIM + lane * 4);
        bf16x4 v2 = *(const bf16x4*)(out1h + (size_t)(p2 & 0xFFFF) * DIM + lane * 4);
        bf16x4 v3 = *(const bf16x4*)(out1h + (size_t)(p3 & 0xFFFF) * DIM + lane * 4);
        f32x4 f0 = (f32x4){(float)v0[0], (float)v0[1], (float)v0[2], (float)v0[3]};
        f32x4 f1 = (f32x4){(float)v1[0], (float)v1[1], (float)v1[2], (float)v1[3]};
        f32x4 f2 = (f32x4){(float)v2[0], (float)v2[1], (float)v2[2], (float)v2[3]};
        f32x4 f3 = (f32x4){(float)v3[0], (float)v3[1], (float)v3[2], (float)v3[3]};
        acc0 += f0 * *(const f32x4*)(relw + (p0 >> 16) * DIM + lane * 4);
        acc1 += f1 * *(const f32x4*)(relw + (p1 >> 16) * DIM + lane * 4);
        acc2 += f2 * *(const f32x4*)(relw + (p2 >> 16) * DIM + lane * 4);
        acc3 += f3 * *(const f32x4*)(relw + (p3 >> 16) * DIM + lane * 4);
    }
    for (; j < e; j++) {
        int p0 = sorted[j];
        bf16x4 v0 = *(const bf16x4*)(out1h + (size_t)(p0 & 0xFFFF) * DIM + lane * 4);
        f32x4 f0 = (f32x4){(float)v0[0], (float)v0[1], (float)v0[2], (float)v0[3]};
        acc0 += f0 * *(const f32x4*)(relw + (p0 >> 16) * DIM + lane * 4);
    }
    acc0 = (acc0 + acc1) + (acc2 + acc3);
    float inv = 1.0f / fmaxf((float)(e - s), 1.0f);
    f32x4 o2 = acc0 * inv;
    bf16x4 eh = *(const bf16x4*)(embh + (size_t)n * DIM + lane * 4);
    bf16x4 o1h = *(const bf16x4*)(out1h + (size_t)n * DIM + lane * 4);
    f32x4 e0 = (f32x4){(float)eh[0], (float)eh[1], (float)eh[2], (float)eh[3]};
    f32x4 o1 = (f32x4){(float)o1h[0], (float)o1h[1], (float)o1h[2], (float)o1h[3]};
    *(f32x4*)(structb + (size_t)b * DIM + lane * 4) = (e0 + o1 + o2) * (1.0f / 3.0f);
}

// ---------------- Head (fused gate+risk1+final) ----------------
// R12: 512 threads / 8 waves; wave w owns 32 output cols (2 column-tiles):
// T = w*2+ct in [0,16) — same gwp/w1p pack mapping.
__launch_bounds__(512)
__global__ void k_head(const float* __restrict__ structb, const float* __restrict__ temporal,
                       const __bf16* __restrict__ gwp, const __bf16* __restrict__ w1p,
                       const float* __restrict__ gate_b, const float* __restrict__ risk_b1,
                       const float* __restrict__ w2s, float* __restrict__ out) {
    int bt = blockIdx.x;
    int tid = threadIdx.x;
    int w = tid >> 6, lane = tid & 63;   // w in [0,8)
    int col = lane & 15, quad = lane >> 4;

    __shared__ __align__(16) __bf16 cat[16][520];
    __shared__ __align__(16) __bf16 mbuf[16][264];
    __shared__ float sacc[16];

    for (int i = tid; i < 16 * 512; i += 512) {
        int m = i >> 9, k = i & 511;
        int b = bt * 16 + m;
        float v = (k < 256) ? structb[(size_t)b * 256 + k]
                            : temporal[(size_t)b * 256 + (k - 256)];
        cat[m][k] = (__bf16)v;
    }
    if (tid < 16) sacc[tid] = 0.0f;
    __syncthreads();

    // gate GEMM: K=512 (16 kc-chunks), wave w owns cols [w*32, w*32+32)
    f32x4 acc[2];
#pragma unroll
    for (int ct = 0; ct < 2; ct++) {
        float b = gate_b[w * 32 + ct * 16 + col];
        acc[ct] = (f32x4){b, b, b, b};
    }
#pragma unroll
    for (int kc = 0; kc < 16; kc++) {
        bf16x8 a = *(const bf16x8*)&cat[col][kc * 32 + quad * 8];
#pragma unroll
        for (int ct = 0; ct < 2; ct++) {
            bf16x8 bf = *(const bf16x8*)(gwp + (((w * 2 + ct) * 16 + kc) << 9) + lane * 8);
            acc[ct] = __builtin_amdgcn_mfma_f32_16x16x32_bf16(a, bf, acc[ct], 0, 0, 0);
        }
    }
    // sigmoid + merge -> mbuf
#pragma unroll
    for (int ct = 0; ct < 2; ct++) {
        int n = w * 32 + ct * 16 + col;
#pragma unroll
        for (int r = 0; r < 4; r++) {
            int m = quad * 4 + r;
            int b = bt * 16 + m;
            float g = sigmoidf_(acc[ct][r]);
            float s = structb[(size_t)b * 256 + n];
            float tm = temporal[(size_t)b * 256 + n];
            mbuf[m][n] = (__bf16)(g * s + (1.0f - g) * tm);
        }
    }
    __syncthreads();

    // risk1 GEMM: K=256 (8 kc-chunks)
    f32x4 acc2[2];
#pragma unroll
    for (int ct = 0; ct < 2; ct++) {
        float b = risk_b1[w * 32 + ct * 16 + col];
        acc2[ct] = (f32x4){b, b, b, b};
    }
#pragma unroll
    for (int kc = 0; kc < 8; kc++) {
        bf16x8 a = *(const bf16x8*)&mbuf[col][kc * 32 + quad * 8];
#pragma unroll
        for (int ct = 0; ct < 2; ct++) {
            bf16x8 bf = *(const bf16x8*)(w1p + (((w * 2 + ct) * 8 + kc) << 9) + lane * 8);
            acc2[ct] = __builtin_amdgcn_mfma_f32_16x16x32_bf16(a, bf, acc2[ct], 0, 0, 0);
        }
    }
    // tanh + dot with w2s, reduce across the 16 lanes of each quad-group
    float part[4] = {0.f, 0.f, 0.f, 0.f};
#pragma unroll
    for (int ct = 0; ct < 2; ct++) {
        int n = w * 32 + ct * 16 + col;
        float wv = w2s[n];
#pragma unroll
        for (int r = 0; r < 4; r++) {
            part[r] += tanhf_(acc2[ct][r]) * wv;
        }
    }
#pragma unroll
    for (int off = 1; off < 16; off <<= 1) {
#pragma unroll
        for (int r = 0; r < 4; r++) part[r] += __shfl_xor(part[r], off, 64);
    }
    if (col == 0) {
#pragma unroll
        for (int r = 0; r < 4; r++) atomicAdd(&sacc[quad * 4 + r], part[r]);
    }
    __syncthreads();
    if (tid < 16) out[bt * 16 + tid] = sigmoidf_(sacc[tid] + w2s[256]);
}

// ---------------- launch ----------------

extern "C" void kernel_launch(void* const* d_in, const int* in_sizes, int n_in,
                              void* d_out, int out_size, void* d_ws, size_t ws_size,
                              hipStream_t stream) {
    const float* ts       = (const float*)d_in[0];
    const float* node_emb = (const float*)d_in[1];
    const float* rel_w    = (const float*)d_in[2];
    const float* gate_W   = (const float*)d_in[3];
    const float* gate_b   = (const float*)d_in[4];
    const float* risk_W1  = (const float*)d_in[5];
    const float* risk_b1  = (const float*)d_in[6];
    const float* risk_W2  = (const float*)d_in[7];
    const float* risk_b2  = (const float*)d_in[8];
    const float* Wih_f    = (const float*)d_in[9];
    const float* Whh_f    = (const float*)d_in[10];
    const float* b_f      = (const float*)d_in[11];
    const float* Wih_b    = (const float*)d_in[12];
    const float* Whh_b    = (const float*)d_in[13];
    const float* b_b      = (const float*)d_in[14];
    const int* edge_index = (const int*)d_in[15];
    const int* edge_type  = (const int*)d_in[16];
    const int* node_idx   = (const int*)d_in[17];
    const int* head = edge_index;
    const int* tail = edge_index + N_EDGES;
    float* out = (float*)d_out;

    char* ws = (char*)d_ws;
    const size_t o_deg      = 0;                            // 50000 int
    const size_t o_flagbuf  = 200704;                       // 50176 B (flagC)
    const size_t o_bsum     = o_flagbuf + 50176;            // 196 int -> pad 1024
    const size_t o_boff     = o_bsum + 1024;                // 256 int (unused since R7)
    const size_t o_offsets  = o_boff + 1024;                // 50001 int -> pad 200960
    const size_t o_cursor   = o_offsets + 200960;           // 50000 int
    const size_t o_sorted   = o_cursor + 200704;            // 300000 int
    const size_t o_out1     = o_sorted + 1200128;           // 25,600,000 B (bf16)
    const size_t o_embh     = o_out1 + 25600000;            // 25,600,000 B (bf16)
    const size_t o_temporal = o_embh + 25600000;            // 4 MB
    const size_t o_struct   = o_temporal + 4194304;         // 4 MB
    const size_t o_gwp      = o_struct + 4194304;           // 262144 B
    const size_t o_w1p      = o_gwp + 262144;               // 131072 B
    const size_t o_w2s      = o_w1p + 131072;               // 257 f -> pad 2048
    const size_t o_w2frag   = o_w2s + 2048;                 // 393216 B
    const size_t o_flagB    = o_w2frag + 393216;            // 50176 B (batch-node flags)
    const size_t o_p32      = o_flagB + 50176;              // 32*256 f = 32768 B (R11)

    int*    deg      = (int*)(ws + o_deg);
    char*   flagC    = (char*)(ws + o_flagbuf);
    char*   flagB    = (char*)(ws + o_flagB);
    int*    bsum     = (int*)(ws + o_bsum);
    int*    offsets  = (int*)(ws + o_offsets);
    int*    cursor   = (int*)(ws + o_cursor);
    int*    sorted   = (int*)(ws + o_sorted);
    __bf16* out1h    = (__bf16*)(ws + o_out1);
    __bf16* embh     = (__bf16*)(ws + o_embh);
    float*  temporal = (float*)(ws + o_temporal);
    float*  structb  = (float*)(ws + o_struct);
    __bf16* gwp      = (__bf16*)(ws + o_gwp);
    __bf16* w1p      = (__bf16*)(ws + o_w1p);
    float*  w2s      = (float*)(ws + o_w2s);
    __bf16* w2frag   = (__bf16*)(ws + o_w2frag);
    float*  p32      = (float*)(ws + o_p32);

    // fused prep: weight packs + w2 partials + zero deg/flagC/flagB + emb->bf16
    k_prep<<<8112, 256, 0, stream>>>(Wih_f, Whh_f, Wih_b, Whh_b, gate_W, risk_W1,
                                     risk_W2, node_emb, w2frag, gwp, w1p,
                                     p32, deg, (int*)flagC, (int*)flagB, embh);
    // sort (R11: k_bsum's extra block folds w2 partials -> w2s)
    k_hist<<<(N_EDGES + 255) / 256, 256, 0, stream>>>(head, node_idx, deg, flagB, flagC);
    k_bsum<<<SCAN_BLOCKS + 1, 256, 0, stream>>>(deg, bsum, p32, risk_b2, w2s);
    k_scan2<<<SCAN_BLOCKS, 256, 0, stream>>>(deg, bsum, offsets, cursor);
    k_place<<<(N_EDGES + 255) / 256, 256, 0, stream>>>(head, tail, edge_type, cursor,
                                                       sorted, flagB, flagC);
    // main chain (R13: lstm split into two half-batch launches for profiling
    // visibility — per-block time unchanged, exposes tail kernels >51us)
    k_gather<<<(N_NODES + 3) / 4, 256, 0, stream>>>(offsets, sorted, rel_w, embh, flagC, out1h);
    k_lstm<<<dim3(64, 2), 512, 0, stream>>>(ts, w2frag, b_f, b_b, temporal, 0);
    k_lstm<<<dim3(64, 2), 512, 0, stream>>>(ts, w2frag, b_f, b_b, temporal, 64);
    k_gather2<<<BATCH / 4, 256, 0, stream>>>(node_idx, offsets, sorted, rel_w, out1h, embh, structb);
    k_head<<<BATCH / 16, 512, 0, stream>>>(structb, temporal, gwp, w1p, gate_b, risk_b1, w2s, out);
}

// Round 15
// 301.518 us; speedup vs baseline: 1.2697x; 1.2697x over previous
//
#include <hip/hip_runtime.h>

#define N_NODES 50000
#define N_EDGES 300000
#define DIM 256
#define HID 128
#define INP 64
#define BATCH 4096
#define SEQ 50
#define SCAN_BLOCKS 196   // ceil(50000/256)

typedef float f32x2 __attribute__((ext_vector_type(2)));
typedef float f32x4 __attribute__((ext_vector_type(4)));
typedef __bf16 bf16x2 __attribute__((ext_vector_type(2)));
typedef __bf16 bf16x4 __attribute__((ext_vector_type(4)));
typedef __bf16 bf16x8 __attribute__((ext_vector_type(8)));

#define L2E  1.4426950408889634f
#define L2E2 2.8853900817779268f

// fast activations: v_rcp_f32 instead of IEEE divide (~1 ulp, inf-safe)
__device__ __forceinline__ float sigmoidf_(float x) {
    return __builtin_amdgcn_rcpf(1.0f + __expf(-x));
}
__device__ __forceinline__ float tanhf_(float x) {
    return 1.0f - 2.0f * __builtin_amdgcn_rcpf(1.0f + __expf(2.0f * x));
}
// prescaled variants: inputs already multiplied by log2e (sig) / 2*log2e (tanh)
// via weight/bias prescale in k_prep -> saves the per-activation log2e mul.
// R2 post-mortem: __builtin_exp2f lowers to llvm.exp2 -> backend emits a
// denormal-range GUARD (~6 ops) -> VALU +45%. __builtin_amdgcn_exp2f is the
// raw v_exp_f32 (1 op); gate inputs are O(1), denormals impossible. (R3 ✓)
__device__ __forceinline__ float sigp_(float y) {
    return __builtin_amdgcn_rcpf(1.0f + __builtin_amdgcn_exp2f(-y));
}
__device__ __forceinline__ float tanhp_(float y) {
    return 1.0f - 2.0f * __builtin_amdgcn_rcpf(1.0f + __builtin_amdgcn_exp2f(y));
}
__device__ __forceinline__ float tanhc_(float x) {   // runtime (unscaled) arg
    return 1.0f - 2.0f * __builtin_amdgcn_rcpf(1.0f + __builtin_amdgcn_exp2f(x * L2E2));
}

// Workgroup barrier WITHOUT the vmcnt(0) drain __syncthreads() emits.
__device__ __forceinline__ void barrier_lds_only() {
    asm volatile("s_waitcnt lgkmcnt(0)" ::: "memory");
    __builtin_amdgcn_s_barrier();
}

// BANKED lessons:
// R8: cooperative grid.sync() ~110us/sync at 1172 blocks. Launch gaps ~1-2us.
// R9: atomic cost scales with per-address collisions (coarse hist = 180us).
// R11: serial poles hide inside big grids (prep's 1-block colsum).
// R12: k_head 1 block/CU x 4 waves = zero TLP -> 8us; 8 waves -> 4us.
// R13: CANNOT profile-split a chain-bound kernel: k_lstm duration = per-block
//     50-step chain (~92us at half load, ~102 full -> ~10% is cross-CU
//     contention); two half launches = 2x full time (+80us). Reverted.
//     Split DID bound every tail kernel < 91us; with upper-bound models
//     (prep<=30, gather~17, sort~7, gather2<=10, head~4, gaps~12) the
//     attributable tail <= ~80us vs measured ~200us -> residual ~120us+ is
//     harness reset (hipMemsetAsync re-poison) inside the timed graph.

// ---------------- fused prep: weight packs + w2 partials + zeroing + emb->bf16
// blocks 0..767: lstm weight frags | 768..1279: gate_W pack | 1280..1535: risk_W1
// 1536..1567: w2 colsum partials (32 blocks x 8 rows, coalesced — R11)
// 1568..1763: zero deg | 1764..1812: zero flagC | 1813..1861: zero flagB
// 1862..8111: node_emb f32->bf16 (R4)
__global__ void k_prep(const float* __restrict__ Wih_f, const float* __restrict__ Whh_f,
                       const float* __restrict__ Wih_b, const float* __restrict__ Whh_b,
                       const float* __restrict__ gate_W, const float* __restrict__ risk_W1,
                       const float* __restrict__ risk_W2,
                       const float* __restrict__ node_emb,
                       __bf16* __restrict__ w2frag, __bf16* __restrict__ gwp,
                       __bf16* __restrict__ w1p, float* __restrict__ p32,
                       int* __restrict__ deg, int* __restrict__ flagCi,
                       int* __restrict__ flagBi, __bf16* __restrict__ embh) {
    int bid = blockIdx.x, tid = threadIdx.x;
    if (bid < 768) {
        // LSTM W=[Wih|Whh] -> frags: per dir frag=(w*4+g)*6+kc, within=lane*8+j
        // weights prescaled: i,f,o gates x log2e ; g (cell) gate x 2*log2e
        int idx = bid * 256 + tid;              // 2*192*512 = 196608
        int dir = idx / 98304;
        int rem = idx % 98304;
        int frag = rem >> 9;
        int within = rem & 511;
        int lane = within >> 3, j = within & 7;
        int kc = frag % 6;
        int wg = frag / 6;
        int g = wg & 3, w = wg >> 2;
        int n = g * 128 + w * 16 + (lane & 15);
        int k = kc * 32 + (lane >> 4) * 8 + j;
        const float* Wih = dir ? Wih_b : Wih_f;
        const float* Whh = dir ? Whh_b : Whh_f;
        float v = (k < 64) ? Wih[n * 64 + k] : Whh[n * 128 + (k - 64)];
        float sc = (g == 2) ? L2E2 : L2E;
        w2frag[idx] = (__bf16)(v * sc);
    } else if (bid < 1280) {
        int idx = (bid - 768) * 256 + tid;      // 131072
        int frag = idx >> 9, within = idx & 511;
        int lane = within >> 3, j = within & 7;
        int kc = frag % 16, T = frag / 16;
        int n = T * 16 + (lane & 15);
        int k = kc * 32 + (lane >> 4) * 8 + j;
        gwp[idx] = (__bf16)gate_W[(size_t)n * 512 + k];
    } else if (bid < 1536) {
        int idx = (bid - 1280) * 256 + tid;     // 65536
        int frag = idx >> 9, within = idx & 511;
        int lane = within >> 3, j = within & 7;
        int kc = frag % 8, T = frag / 8;
        int n = T * 16 + (lane & 15);
        int k = kc * 32 + (lane >> 4) * 8 + j;
        w1p[idx] = (__bf16)risk_W1[(size_t)n * 256 + k];
    } else if (bid < 1568) {
        // w2 colsum partials: block j sums rows [j*8, j*8+8), coalesced rows
        int j = bid - 1536;
        int k = tid;
        float s = 0.0f;
#pragma unroll
        for (int r = 0; r < 8; r++) s += risk_W2[(size_t)(j * 8 + r) * 256 + k];
        p32[j * 256 + k] = s;
    } else if (bid < 1764) {
        int i = (bid - 1568) * 256 + tid;
        if (i < N_NODES) deg[i] = 0;
    } else if (bid < 1813) {
        int i = (bid - 1764) * 256 + tid;       // 49*256 = 12544 ints = 50176 B
        flagCi[i] = 0;
    } else if (bid < 1862) {
        int i = (bid - 1813) * 256 + tid;
        flagBi[i] = 0;
    } else {
        // emb convert: 12,800,000 elems / 8 per thread / 256 thr = 6250 blocks
        int idx = (bid - 1862) * 2048 + tid * 8;
        f32x4 a = *(const f32x4*)(node_emb + idx);
        f32x4 b = *(const f32x4*)(node_emb + idx + 4);
        bf16x8 o;
        o[0] = (__bf16)a.x; o[1] = (__bf16)a.y; o[2] = (__bf16)a.z; o[3] = (__bf16)a.w;
        o[4] = (__bf16)b.x; o[5] = (__bf16)b.y; o[6] = (__bf16)b.z; o[7] = (__bf16)b.w;
        *(bf16x8*)(embh + idx) = o;
    }
}

// ---------------- GCN: counting sort by head ----------------
// R10: deg histogram only (50K counters, ~6 collisions/addr — fine).
// Batch flags set here (prep zeroed them; later launch -> no race).
__global__ void k_hist(const int* __restrict__ head, const int* __restrict__ nidx,
                       int* __restrict__ deg, char* __restrict__ flagB,
                       char* __restrict__ flagC) {
    int e = blockIdx.x * 256 + threadIdx.x;
    if (e < N_EDGES) atomicAdd(&deg[head[e]], 1);
    if (e < BATCH) {
        int n = nidx[e];
        flagB[n] = 1;
        flagC[n] = 1;
    }
}

// per-block sums of deg (sequential read, LDS reduce) — R7-proven form.
// R11: extra block (bid==SCAN_BLOCKS) folds the 32 w2 partials -> w2s[0..255]
// and reduces risk_b2 -> w2s[256] (moved out of k_prep's serial block).
__global__ void k_bsum(const int* __restrict__ deg, int* __restrict__ bsum,
                       const float* __restrict__ p32, const float* __restrict__ risk_b2,
                       float* __restrict__ w2s) {
    __shared__ int red[256];
    __shared__ float redf[256];
    int bid = blockIdx.x, tid = threadIdx.x;
    if (bid < SCAN_BLOCKS) {
        int n = bid * 256 + tid;
        red[tid] = (n < N_NODES) ? deg[n] : 0;
        __syncthreads();
        for (int st = 128; st > 0; st >>= 1) {
            if (tid < st) red[tid] += red[tid + st];
            __syncthreads();
        }
        if (tid == 0) bsum[bid] = red[0];
    } else {
        float s = 0.0f;
#pragma unroll
        for (int j = 0; j < 32; j++) s += p32[j * 256 + tid];
        w2s[tid] = s;
        redf[tid] = risk_b2[tid];
        __syncthreads();
        for (int st = 128; st > 0; st >>= 1) {
            if (tid < st) redf[tid] += redf[tid + st];
            __syncthreads();
        }
        if (tid == 0) w2s[256] = redf[0];
    }
}

// R7: scanb folded in — each block computes its own exclusive block-prefix
// from bsum (second LDS scan in the same barrier loop).
__global__ void k_scan2(const int* __restrict__ deg, const int* __restrict__ bsum,
                        int* __restrict__ offsets, int* __restrict__ cursor) {
    __shared__ int s[256];
    __shared__ int sb[256];
    int i = threadIdx.x;
    int n = blockIdx.x * 256 + i;
    int v = (n < N_NODES) ? deg[n] : 0;
    s[i] = v;
    sb[i] = (i < SCAN_BLOCKS) ? bsum[i] : 0;
    __syncthreads();
    for (int st = 1; st < 256; st <<= 1) {
        int add = (i >= st) ? s[i - st] : 0;
        int addb = (i >= st) ? sb[i - st] : 0;
        __syncthreads();
        s[i] += add;
        sb[i] += addb;
        __syncthreads();
    }
    int boff = (blockIdx.x > 0) ? sb[blockIdx.x - 1] : 0;   // exclusive block prefix
    if (n < N_NODES) {
        int off = boff + s[i] - v;
        offsets[n] = off;
        cursor[n] = off;
    }
    if (n == 0) offsets[N_NODES] = N_EDGES;
}

// R9 (kept): k_flag folded in — per-edge tail-flag: flagC[tail]=1 where
// flagB[head]. flagB marks batch nodes only -> no cascade; identical flag set.
__global__ void k_place(const int* __restrict__ head, const int* __restrict__ tail,
                        const int* __restrict__ etype, int* __restrict__ cursor,
                        int* __restrict__ sorted, const char* __restrict__ flagB,
                        char* __restrict__ flagC) {
    int e = blockIdx.x * 256 + threadIdx.x;
    if (e >= N_EDGES) return;
    int h = head[e];
    int pos = atomicAdd(&cursor[h], 1);
    int t = tail[e];
    sorted[pos] = t | (etype[e] << 16);   // tail<65536, etype<32
    if (flagB[h]) flagC[t] = 1;
}

// Hop 1: one wave per node; only flagged nodes (~43% of graph). No atomics.
// R4: bf16 src rows (8B/lane) + bf16 dst, f32 accumulate.
// R5 post-mortem: do NOT grid-fuse this with k_lstm (critical-path dilution).
__global__ void k_gather(const int* __restrict__ offsets, const int* __restrict__ sorted,
                         const float* __restrict__ relw, const __bf16* __restrict__ srch,
                         const char* __restrict__ flag, __bf16* __restrict__ dst) {
    int tid = threadIdx.x;
    int w = tid >> 6, lane = tid & 63;
    int n = blockIdx.x * 4 + w;
    if (n >= N_NODES) return;
    if (!flag[n]) return;
    int s = offsets[n], e = offsets[n + 1];
    f32x4 acc0 = (f32x4){0.f, 0.f, 0.f, 0.f};
    f32x4 acc1 = (f32x4){0.f, 0.f, 0.f, 0.f};
    f32x4 acc2 = (f32x4){0.f, 0.f, 0.f, 0.f};
    f32x4 acc3 = (f32x4){0.f, 0.f, 0.f, 0.f};
    int j = s;
    for (; j + 4 <= e; j += 4) {
        int p0 = sorted[j], p1 = sorted[j + 1], p2 = sorted[j + 2], p3 = sorted[j + 3];
        bf16x4 v0 = *(const bf16x4*)(srch + (size_t)(p0 & 0xFFFF) * DIM + lane * 4);
        bf16x4 v1 = *(const bf16x4*)(srch + (size_t)(p1 & 0xFFFF) * DIM + lane * 4);
        bf16x4 v2 = *(const bf16x4*)(srch + (size_t)(p2 & 0xFFFF) * DIM + lane * 4);
        bf16x4 v3 = *(const bf16x4*)(srch + (size_t)(p3 & 0xFFFF) * DIM + lane * 4);
        f32x4 f0 = (f32x4){(float)v0[0], (float)v0[1], (float)v0[2], (float)v0[3]};
        f32x4 f1 = (f32x4){(float)v1[0], (float)v1[1], (float)v1[2], (float)v1[3]};
        f32x4 f2 = (f32x4){(float)v2[0], (float)v2[1], (float)v2[2], (float)v2[3]};
        f32x4 f3 = (f32x4){(float)v3[0], (float)v3[1], (float)v3[2], (float)v3[3]};
        acc0 += f0 * *(const f32x4*)(relw + (p0 >> 16) * DIM + lane * 4);
        acc1 += f1 * *(const f32x4*)(relw + (p1 >> 16) * DIM + lane * 4);
        acc2 += f2 * *(const f32x4*)(relw + (p2 >> 16) * DIM + lane * 4);
        acc3 += f3 * *(const f32x4*)(relw + (p3 >> 16) * DIM + lane * 4);
    }
    for (; j < e; j++) {
        int p0 = sorted[j];
        bf16x4 v0 = *(const bf16x4*)(srch + (size_t)(p0 & 0xFFFF) * DIM + lane * 4);
        f32x4 f0 = (f32x4){(float)v0[0], (float)v0[1], (float)v0[2], (float)v0[3]};
        acc0 += f0 * *(const f32x4*)(relw + (p0 >> 16) * DIM + lane * 4);
    }
    acc0 = (acc0 + acc1) + (acc2 + acc3);
    float inv = 1.0f / fmaxf((float)(e - s), 1.0f);
    acc0 *= inv;
    bf16x4 o;
    o[0] = (__bf16)acc0.x; o[1] = (__bf16)acc0.y; o[2] = (__bf16)acc0.z; o[3] = (__bf16)acc0.w;
    *(bf16x4*)(dst + (size_t)n * DIM + lane * 4) = o;
}

// ---------------- BiLSTM: intra-wave 2-group software pipeline (R4 config) ---
// Block = 8 waves (512 thr), 2 groups x 16 samples, one dir. Grid (128,2)=256.
// OCCUPANCY IS LOCKED at 2 waves/SIMD, 1 block/CU:
//  - R1/R2: __launch_bounds__ min-waves coercion -> VGPR 64 -> spill (588MB).
//  - R6: 1-group blocks at natural VGPR 84 (<128, no spill) still did NOT
//    co-reside. Compile-time 2-group interleave > inter-block overlap.
//  - R13: duration = per-block 50-step chain; do NOT split the launch.
// R3 opts: exp2-prescale (raw v_exp_f32), bias-as-C-init, ptr-increment prefetch,
// lgkm-only barriers.
__launch_bounds__(512)
__global__ void k_lstm(const float* __restrict__ ts, const __bf16* __restrict__ w2frag,
                       const float* __restrict__ b_f, const float* __restrict__ b_b,
                       float* __restrict__ temporal) {
    int dir = blockIdx.y;
    int btile = blockIdx.x;    // 0..127
    int tid = threadIdx.x;
    int w = tid >> 6;          // wave 0..7
    int lane = tid & 63;
    int col = lane & 15, quad = lane >> 4;

    // [buf][row][k], rows 16, k: 0..63 = x, 64..191 = h, padded to 200 (16B-aligned rows)
    __shared__ __align__(16) __bf16 SA[2 * 16 * 200];
    __shared__ __align__(16) __bf16 SB[2 * 16 * 200];

    // zero h region of buf 0, both groups (h(-1) = 0)
    for (int i = tid; i < 2048; i += 512) {
        int m = i >> 7, k = i & 127;
        SA[m * 200 + 64 + k] = (__bf16)0.0f;
        SB[m * 200 + 64 + k] = (__bf16)0.0f;
    }

    const float* bias = dir ? b_b : b_f;
    f32x4 bva[4];
#pragma unroll
    for (int g = 0; g < 4; g++) {
        float b = bias[g * 128 + w * 16 + col] * ((g == 2) ? L2E2 : L2E);
        bva[g] = (f32x4){b, b, b, b};
    }

    const __bf16* wbase = w2frag + (size_t)dir * 98304 + (size_t)w * 12288;
    bf16x8 wreg[24];
#pragma unroll
    for (int f = 0; f < 24; f++) {
        wreg[f] = *(const bf16x8*)(wbase + (f << 9) + lane * 8);
    }

    // x staging: 16 rows x 64 cols per group; thread -> (sm, sc)
    int sm = tid >> 5, sc = (tid & 31) * 2;
    const float* xbA = ts + ((size_t)(btile * 32 + sm) * SEQ) * INP + sc;
    const float* xbB = ts + ((size_t)(btile * 32 + 16 + sm) * SEQ) * INP + sc;
    int t0i = dir ? (SEQ - 1) : 0;
    int t1i = dir ? (SEQ - 2) : 1;
    {   // stage x(0) for both groups into buf 0
        f32x2 xa = *(const f32x2*)(xbA + (size_t)t0i * INP);
        f32x2 xb = *(const f32x2*)(xbB + (size_t)t0i * INP);
        bf16x2 va; va[0] = (__bf16)xa.x; va[1] = (__bf16)xa.y;
        bf16x2 vb; vb[0] = (__bf16)xb.x; vb[1] = (__bf16)xb.y;
        *(bf16x2*)&SA[sm * 200 + sc] = va;
        *(bf16x2*)&SB[sm * 200 + sc] = vb;
    }
    f32x2 xpreA = *(const f32x2*)(xbA + (size_t)t1i * INP);
    f32x2 xpreB = *(const f32x2*)(xbB + (size_t)t1i * INP);
    // prefetch pointers start at x(t=2), walk +/-INP per step
    int xdelta = dir ? -INP : INP;
    const float* pA = xbA + (size_t)(dir ? (SEQ - 3) : 2) * INP;
    const float* pB = xbB + (size_t)(dir ? (SEQ - 3) : 2) * INP;

    f32x4 cA = (f32x4){0.f, 0.f, 0.f, 0.f}, hsA = cA;
    f32x4 cB = cA, hsB = cA;
    f32x4 accA[4], accB[4];
    int hwr = quad * 4 * 200 + 64 + w * 16 + col;   // h write base (row=quad*4, +r*200)
    int ard = col * 200 + quad * 8;                  // A-frag read base
    barrier_lds_only();

    // prologue MFMA-A(0) from SA buf 0 (bias folded in via C-init)
    {
        bf16x8 a0 = *(const bf16x8*)&SA[ard];
#pragma unroll
        for (int g = 0; g < 4; g++)
            accA[g] = __builtin_amdgcn_mfma_f32_16x16x32_bf16(a0, wreg[g * 6], bva[g], 0, 0, 0);
    }
#pragma unroll
    for (int kc = 1; kc < 6; kc++) {
        bf16x8 a0 = *(const bf16x8*)&SA[ard + kc * 32];
#pragma unroll
        for (int g = 0; g < 4; g++)
            accA[g] = __builtin_amdgcn_mfma_f32_16x16x32_bf16(a0, wreg[g * 6 + kc], accA[g], 0, 0, 0);
    }

    for (int t = 0; t < SEQ; t++) {
        int cb = (t & 1) * 3200;         // current buf offset
        int nb = ((t + 1) & 1) * 3200;   // next buf offset

        // ---- first half: MFMA-B(t) (reads SB[cb]) || cell-A(t) (writes SA[nb]) ----
        f32x2 xnA;
        bool ld = (t + 2 < SEQ);         // wave-uniform
        if (ld) { xnA = *(const f32x2*)pA; pA += xdelta; }
        {
            bf16x8 a0 = *(const bf16x8*)&SB[cb + ard];
#pragma unroll
            for (int g = 0; g < 4; g++)
                accB[g] = __builtin_amdgcn_mfma_f32_16x16x32_bf16(a0, wreg[g * 6], bva[g], 0, 0, 0);
        }
#pragma unroll
        for (int kc = 1; kc < 6; kc++) {
            bf16x8 a0 = *(const bf16x8*)&SB[cb + ard + kc * 32];
#pragma unroll
            for (int g = 0; g < 4; g++)
                accB[g] = __builtin_amdgcn_mfma_f32_16x16x32_bf16(a0, wreg[g * 6 + kc], accB[g], 0, 0, 0);
        }
#pragma unroll
        for (int r = 0; r < 4; r++) {
            float c = sigp_(accA[1][r]) * cA[r] + sigp_(accA[0][r]) * tanhp_(accA[2][r]);
            float h = sigp_(accA[3][r]) * tanhc_(c);
            cA[r] = c;
            hsA[r] += h;
            SA[nb + hwr + r * 200] = (__bf16)h;
        }
        if (t + 1 < SEQ) {
            bf16x2 v; v[0] = (__bf16)xpreA.x; v[1] = (__bf16)xpreA.y;
            *(bf16x2*)&SA[nb + sm * 200 + sc] = v;
            if (ld) xpreA = xnA;
        }
        barrier_lds_only();

        // ---- second half: MFMA-A(t+1) (reads SA[nb]) || cell-B(t) (writes SB[nb]) ----
        f32x2 xnB;
        if (ld) { xnB = *(const f32x2*)pB; pB += xdelta; }
        if (t + 1 < SEQ) {
            {
                bf16x8 a0 = *(const bf16x8*)&SA[nb + ard];
#pragma unroll
                for (int g = 0; g < 4; g++)
                    accA[g] = __builtin_amdgcn_mfma_f32_16x16x32_bf16(a0, wreg[g * 6], bva[g], 0, 0, 0);
            }
#pragma unroll
            for (int kc = 1; kc < 6; kc++) {
                bf16x8 a0 = *(const bf16x8*)&SA[nb + ard + kc * 32];
#pragma unroll
                for (int g = 0; g < 4; g++)
                    accA[g] = __builtin_amdgcn_mfma_f32_16x16x32_bf16(a0, wreg[g * 6 + kc], accA[g], 0, 0, 0);
            }
        }
#pragma unroll
        for (int r = 0; r < 4; r++) {
            float c = sigp_(accB[1][r]) * cB[r] + sigp_(accB[0][r]) * tanhp_(accB[2][r]);
            float h = sigp_(accB[3][r]) * tanhc_(c);
            cB[r] = c;
            hsB[r] += h;
            SB[nb + hwr + r * 200] = (__bf16)h;
        }
        if (t + 1 < SEQ) {
            bf16x2 v; v[0] = (__bf16)xpreB.x; v[1] = (__bf16)xpreB.y;
            *(bf16x2*)&SB[nb + sm * 200 + sc] = v;
            if (ld) xpreB = xnB;
        }
        barrier_lds_only();
    }

    // temporal[b][dir*128 + j] = mean over t of h
#pragma unroll
    for (int r = 0; r < 4; r++) {
        int j = w * 16 + col;
        int bA = btile * 32 + quad * 4 + r;
        int bB = bA + 16;
        temporal[(size_t)bA * 256 + dir * 128 + j] = hsA[r] * (1.0f / SEQ);
        temporal[(size_t)bB * 256 + dir * 128 + j] = hsB[r] * (1.0f / SEQ);
    }
}

// Hop 2 only at batch nodes, fused with struct = (emb + out1 + out2)/3.
// R4: bf16 out1/emb reads, f32 accumulate, f32 struct output (unchanged dtype).
__global__ void k_gather2(const int* __restrict__ nidx, const int* __restrict__ offsets,
                          const int* __restrict__ sorted, const float* __restrict__ relw,
                          const __bf16* __restrict__ out1h, const __bf16* __restrict__ embh,
                          float* __restrict__ structb) {
    int tid = threadIdx.x;
    int w = tid >> 6, lane = tid & 63;
    int b = blockIdx.x * 4 + w;          // grid = 1024 blocks, exact
    int n = nidx[b];
    int s = offsets[n], e = offsets[n + 1];
    f32x4 acc0 = (f32x4){0.f, 0.f, 0.f, 0.f};
    f32x4 acc1 = (f32x4){0.f, 0.f, 0.f, 0.f};
    f32x4 acc2 = (f32x4){0.f, 0.f, 0.f, 0.f};
    f32x4 acc3 = (f32x4){0.f, 0.f, 0.f, 0.f};
    int j = s;
    for (; j + 4 <= e; j += 4) {
        int p0 = sorted[j], p1 = sorted[j + 1], p2 = sorted[j + 2], p3 = sorted[j + 3];
        bf16x4 v0 = *(const bf16x4*)(out1h + (size_t)(p0 & 0xFFFF) * DIM + lane * 4);
        bf16x4 v1 = *(const bf16x4*)(out1h + (size_t)(p1 & 0xFFFF) * DIM + lane * 4);
        bf16x4 v2 = *(const bf16x4*)(out1h + (size_t)(p2 & 0xFFFF) * DIM + lane * 4);
        bf16x4 v3 = *(const bf16x4*)(out1h + (size_t)(p3 & 0xFFFF) * DIM + lane * 4);
        f32x4 f0 = (f32x4){(float)v0[0], (float)v0[1], (float)v0[2], (float)v0[3]};
        f32x4 f1 = (f32x4){(float)v1[0], (float)v1[1], (float)v1[2], (float)v1[3]};
        f32x4 f2 = (f32x4){(float)v2[0], (float)v2[1], (float)v2[2], (float)v2[3]};
        f32x4 f3 = (f32x4){(float)v3[0], (float)v3[1], (float)v3[2], (float)v3[3]};
        acc0 += f0 * *(const f32x4*)(relw + (p0 >> 16) * DIM + lane * 4);
        acc1 += f1 * *(const f32x4*)(relw + (p1 >> 16) * DIM + lane * 4);
        acc2 += f2 * *(const f32x4*)(relw + (p2 >> 16) * DIM + lane * 4);
        acc3 += f3 * *(const f32x4*)(relw + (p3 >> 16) * DIM + lane * 4);
    }
    for (; j < e; j++) {
        int p0 = sorted[j];
        bf16x4 v0 = *(const bf16x4*)(out1h + (size_t)(p0 & 0xFFFF) * DIM + lane * 4);
        f32x4 f0 = (f32x4){(float)v0[0], (float)v0[1], (float)v0[2], (float)v0[3]};
        acc0 += f0 * *(const f32x4*)(relw + (p0 >> 16) * DIM + lane * 4);
    }
    acc0 = (acc0 + acc1) + (acc2 + acc3);
    float inv = 1.0f / fmaxf((float)(e - s), 1.0f);
    f32x4 o2 = acc0 * inv;
    bf16x4 eh = *(const bf16x4*)(embh + (size_t)n * DIM + lane * 4);
    bf16x4 o1h = *(const bf16x4*)(out1h + (size_t)n * DIM + lane * 4);
    f32x4 e0 = (f32x4){(float)eh[0], (float)eh[1], (float)eh[2], (float)eh[3]};
    f32x4 o1 = (f32x4){(float)o1h[0], (float)o1h[1], (float)o1h[2], (float)o1h[3]};
    *(f32x4*)(structb + (size_t)b * DIM + lane * 4) = (e0 + o1 + o2) * (1.0f / 3.0f);
}

// ---------------- Head (fused gate+risk1+final) ----------------
// R12: 512 threads / 8 waves; wave w owns 32 output cols (2 column-tiles):
// T = w*2+ct in [0,16) — same gwp/w1p pack mapping.
__launch_bounds__(512)
__global__ void k_head(const float* __restrict__ structb, const float* __restrict__ temporal,
                       const __bf16* __restrict__ gwp, const __bf16* __restrict__ w1p,
                       const float* __restrict__ gate_b, const float* __restrict__ risk_b1,
                       const float* __restrict__ w2s, float* __restrict__ out) {
    int bt = blockIdx.x;
    int tid = threadIdx.x;
    int w = tid >> 6, lane = tid & 63;   // w in [0,8)
    int col = lane & 15, quad = lane >> 4;

    __shared__ __align__(16) __bf16 cat[16][520];
    __shared__ __align__(16) __bf16 mbuf[16][264];
    __shared__ float sacc[16];

    for (int i = tid; i < 16 * 512; i += 512) {
        int m = i >> 9, k = i & 511;
        int b = bt * 16 + m;
        float v = (k < 256) ? structb[(size_t)b * 256 + k]
                            : temporal[(size_t)b * 256 + (k - 256)];
        cat[m][k] = (__bf16)v;
    }
    if (tid < 16) sacc[tid] = 0.0f;
    __syncthreads();

    // gate GEMM: K=512 (16 kc-chunks), wave w owns cols [w*32, w*32+32)
    f32x4 acc[2];
#pragma unroll
    for (int ct = 0; ct < 2; ct++) {
        float b = gate_b[w * 32 + ct * 16 + col];
        acc[ct] = (f32x4){b, b, b, b};
    }
#pragma unroll
    for (int kc = 0; kc < 16; kc++) {
        bf16x8 a = *(const bf16x8*)&cat[col][kc * 32 + quad * 8];
#pragma unroll
        for (int ct = 0; ct < 2; ct++) {
            bf16x8 bf = *(const bf16x8*)(gwp + (((w * 2 + ct) * 16 + kc) << 9) + lane * 8);
            acc[ct] = __builtin_amdgcn_mfma_f32_16x16x32_bf16(a, bf, acc[ct], 0, 0, 0);
        }
    }
    // sigmoid + merge -> mbuf
#pragma unroll
    for (int ct = 0; ct < 2; ct++) {
        int n = w * 32 + ct * 16 + col;
#pragma unroll
        for (int r = 0; r < 4; r++) {
            int m = quad * 4 + r;
            int b = bt * 16 + m;
            float g = sigmoidf_(acc[ct][r]);
            float s = structb[(size_t)b * 256 + n];
            float tm = temporal[(size_t)b * 256 + n];
            mbuf[m][n] = (__bf16)(g * s + (1.0f - g) * tm);
        }
    }
    __syncthreads();

    // risk1 GEMM: K=256 (8 kc-chunks)
    f32x4 acc2[2];
#pragma unroll
    for (int ct = 0; ct < 2; ct++) {
        float b = risk_b1[w * 32 + ct * 16 + col];
        acc2[ct] = (f32x4){b, b, b, b};
    }
#pragma unroll
    for (int kc = 0; kc < 8; kc++) {
        bf16x8 a = *(const bf16x8*)&mbuf[col][kc * 32 + quad * 8];
#pragma unroll
        for (int ct = 0; ct < 2; ct++) {
            bf16x8 bf = *(const bf16x8*)(w1p + (((w * 2 + ct) * 8 + kc) << 9) + lane * 8);
            acc2[ct] = __builtin_amdgcn_mfma_f32_16x16x32_bf16(a, bf, acc2[ct], 0, 0, 0);
        }
    }
    // tanh + dot with w2s, reduce across the 16 lanes of each quad-group
    float part[4] = {0.f, 0.f, 0.f, 0.f};
#pragma unroll
    for (int ct = 0; ct < 2; ct++) {
        int n = w * 32 + ct * 16 + col;
        float wv = w2s[n];
#pragma unroll
        for (int r = 0; r < 4; r++) {
            part[r] += tanhf_(acc2[ct][r]) * wv;
        }
    }
#pragma unroll
    for (int off = 1; off < 16; off <<= 1) {
#pragma unroll
        for (int r = 0; r < 4; r++) part[r] += __shfl_xor(part[r], off, 64);
    }
    if (col == 0) {
#pragma unroll
        for (int r = 0; r < 4; r++) atomicAdd(&sacc[quad * 4 + r], part[r]);
    }
    __syncthreads();
    if (tid < 16) out[bt * 16 + tid] = sigmoidf_(sacc[tid] + w2s[256]);
}

// ---------------- launch ----------------

extern "C" void kernel_launch(void* const* d_in, const int* in_sizes, int n_in,
                              void* d_out, int out_size, void* d_ws, size_t ws_size,
                              hipStream_t stream) {
    const float* ts       = (const float*)d_in[0];
    const float* node_emb = (const float*)d_in[1];
    const float* rel_w    = (const float*)d_in[2];
    const float* gate_W   = (const float*)d_in[3];
    const float* gate_b   = (const float*)d_in[4];
    const float* risk_W1  = (const float*)d_in[5];
    const float* risk_b1  = (const float*)d_in[6];
    const float* risk_W2  = (const float*)d_in[7];
    const float* risk_b2  = (const float*)d_in[8];
    const float* Wih_f    = (const float*)d_in[9];
    const float* Whh_f    = (const float*)d_in[10];
    const float* b_f      = (const float*)d_in[11];
    const float* Wih_b    = (const float*)d_in[12];
    const float* Whh_b    = (const float*)d_in[13];
    const float* b_b      = (const float*)d_in[14];
    const int* edge_index = (const int*)d_in[15];
    const int* edge_type  = (const int*)d_in[16];
    const int* node_idx   = (const int*)d_in[17];
    const int* head = edge_index;
    const int* tail = edge_index + N_EDGES;
    float* out = (float*)d_out;

    char* ws = (char*)d_ws;
    const size_t o_deg      = 0;                            // 50000 int
    const size_t o_flagbuf  = 200704;                       // 50176 B (flagC)
    const size_t o_bsum     = o_flagbuf + 50176;            // 196 int -> pad 1024
    const size_t o_boff     = o_bsum + 1024;                // 256 int (unused since R7)
    const size_t o_offsets  = o_boff + 1024;                // 50001 int -> pad 200960
    const size_t o_cursor   = o_offsets + 200960;           // 50000 int
    const size_t o_sorted   = o_cursor + 200704;            // 300000 int
    const size_t o_out1     = o_sorted + 1200128;           // 25,600,000 B (bf16)
    const size_t o_embh     = o_out1 + 25600000;            // 25,600,000 B (bf16)
    const size_t o_temporal = o_embh + 25600000;            // 4 MB
    const size_t o_struct   = o_temporal + 4194304;         // 4 MB
    const size_t o_gwp      = o_struct + 4194304;           // 262144 B
    const size_t o_w1p      = o_gwp + 262144;               // 131072 B
    const size_t o_w2s      = o_w1p + 131072;               // 257 f -> pad 2048
    const size_t o_w2frag   = o_w2s + 2048;                 // 393216 B
    const size_t o_flagB    = o_w2frag + 393216;            // 50176 B (batch-node flags)
    const size_t o_p32      = o_flagB + 50176;              // 32*256 f = 32768 B (R11)

    int*    deg      = (int*)(ws + o_deg);
    char*   flagC    = (char*)(ws + o_flagbuf);
    char*   flagB    = (char*)(ws + o_flagB);
    int*    bsum     = (int*)(ws + o_bsum);
    int*    offsets  = (int*)(ws + o_offsets);
    int*    cursor   = (int*)(ws + o_cursor);
    int*    sorted   = (int*)(ws + o_sorted);
    __bf16* out1h    = (__bf16*)(ws + o_out1);
    __bf16* embh     = (__bf16*)(ws + o_embh);
    float*  temporal = (float*)(ws + o_temporal);
    float*  structb  = (float*)(ws + o_struct);
    __bf16* gwp      = (__bf16*)(ws + o_gwp);
    __bf16* w1p      = (__bf16*)(ws + o_w1p);
    float*  w2s      = (float*)(ws + o_w2s);
    __bf16* w2frag   = (__bf16*)(ws + o_w2frag);
    float*  p32      = (float*)(ws + o_p32);

    // fused prep: weight packs + w2 partials + zero deg/flagC/flagB + emb->bf16
    k_prep<<<8112, 256, 0, stream>>>(Wih_f, Whh_f, Wih_b, Whh_b, gate_W, risk_W1,
                                     risk_W2, node_emb, w2frag, gwp, w1p,
                                     p32, deg, (int*)flagC, (int*)flagB, embh);
    // sort (R11: k_bsum's extra block folds w2 partials -> w2s)
    k_hist<<<(N_EDGES + 255) / 256, 256, 0, stream>>>(head, node_idx, deg, flagB, flagC);
    k_bsum<<<SCAN_BLOCKS + 1, 256, 0, stream>>>(deg, bsum, p32, risk_b2, w2s);
    k_scan2<<<SCAN_BLOCKS, 256, 0, stream>>>(deg, bsum, offsets, cursor);
    k_place<<<(N_EDGES + 255) / 256, 256, 0, stream>>>(head, tail, edge_type, cursor,
                                                       sorted, flagB, flagC);
    // main chain (single lstm launch — R13: duration is per-block chain time)
    k_gather<<<(N_NODES + 3) / 4, 256, 0, stream>>>(offsets, sorted, rel_w, embh, flagC, out1h);
    k_lstm<<<dim3(BATCH / 32, 2), 512, 0, stream>>>(ts, w2frag, b_f, b_b, temporal);
    k_gather2<<<BATCH / 4, 256, 0, stream>>>(node_idx, offsets, sorted, rel_w, out1h, embh, structb);
    k_head<<<BATCH / 16, 512, 0, stream>>>(structb, temporal, gwp, w1p, gate_b, risk_b1, w2s, out);
}